// Round 6
// baseline (126.190 us; speedup 1.0000x reference)
//
#include <hip/hip_runtime.h>
#include <hip/hip_bf16.h>

namespace {

constexpr int T_DIM = 16384;   // number of tiles
constexpr int NT    = 8;       // tiles per block -> grid = 2048 (6 blocks/CU resident)

typedef __attribute__((ext_vector_type(8))) short bf16x8;
typedef __attribute__((ext_vector_type(4))) float f32x4;

__device__ inline short f2bf(float f) {
    union { __hip_bfloat16 h; short s; } u;
    u.h = __float2bfloat16(f);
    return u.s;
}

__device__ inline bf16x8 cvt8(f32x4 a, f32x4 b) {
    bf16x8 r;
    r[0] = f2bf(a[0]); r[1] = f2bf(a[1]); r[2] = f2bf(a[2]); r[3] = f2bf(a[3]);
    r[4] = f2bf(b[0]); r[5] = f2bf(b[1]); r[6] = f2bf(b[2]); r[7] = f2bf(b[3]);
    return r;
}

} // namespace

// R2 schedule (best so far) + occupancy lever:
//  - W1 staged as BF16 (reg-stage: coalesced 64B/lane f32 load -> cvt ->
//    swizzled ds_write_b128). Tile 8KB, dbuf 16KB LDS.
//  - T14 split: stage loads issued BEFORE compute, cvt+write AFTER, one
//    __syncthreads per tile (drains vmcnt+lgkm; TLP across 6 blocks hides it).
//  - Swizzle: LDS holds semantic bf16 byte b at addr b ^ (((b>>7)&7)<<4)
//    (write-side swizzle; reads use the same mask). Both sides ~conflict-free.
//  - NT=8 -> 2048 blocks -> 6 blocks/CU (24 waves/CU vs R2's ~17).
__global__ __launch_bounds__(256, 6) void fgbn_kernel(
    const float* __restrict__ x,
    const float* __restrict__ W1,
    const float* __restrict__ b1,
    const float* __restrict__ W2,
    const float* __restrict__ b2,
    float* __restrict__ out)
{
    __shared__ short tile[2][4096];   // 2 x 8KB bf16 W1 tiles

    const int tid  = threadIdx.x;
    const int lane = tid & 63;
    const int wave = tid >> 6;
    const int l15  = lane & 15;
    const int l4   = lane >> 4;
    const int t0   = blockIdx.x * NT;

    // A fragments from x: A[row=lane&15][k=8*(lane>>4)+e]; wave w owns rows
    // [32w, 32w+32) as two 16-row fragments.
    bf16x8 afrag[2][2];   // [rf][ks]
    #pragma unroll
    for (int rf = 0; rf < 2; ++rf) {
        const int row = wave * 32 + rf * 16 + l15;
        #pragma unroll
        for (int ks = 0; ks < 2; ++ks) {
            const float* src = x + row * 64 + ks * 32 + l4 * 8;
            afrag[rf][ks] = cvt8(*reinterpret_cast<const f32x4*>(src),
                                 *reinterpret_cast<const f32x4*>(src + 4));
        }
    }
    // Lane keeps b2[t0 + l15]; the surviving lane l15==ti consumes it (NT<=16).
    const float b2lane = b2[t0 + l15];

    // ---- Stage: lane owns f32 elements [tid*16, tid*16+16) of the tile ----
    // (64B/lane, perfectly coalesced: wave covers 4KB contiguous).
    f32x4 r0, r1, r2, r3;   // named regs: all indexing compile-time
    auto stage_load = [&](int t) {
        const float* src = W1 + (size_t)t * 4096 + tid * 16;
        r0 = *reinterpret_cast<const f32x4*>(src);
        r1 = *reinterpret_cast<const f32x4*>(src + 4);
        r2 = *reinterpret_cast<const f32x4*>(src + 8);
        r3 = *reinterpret_cast<const f32x4*>(src + 12);
    };
    // Lane's 16 bf16 -> LDS linear bytes [tid*32, tid*32+32), swizzled.
    auto stage_write = [&](int buf) {
        char* lb = (char*)&tile[buf][0];
        const int swz = ((tid >> 2) & 7) << 4;   // j = tid>>2 for both halves
        const int b0  = tid * 32;
        *reinterpret_cast<bf16x8*>(lb + (b0 ^ swz))        = cvt8(r0, r1);
        *reinterpret_cast<bf16x8*>(lb + ((b0 + 16) ^ swz)) = cvt8(r2, r3);
    };

    stage_load(t0);
    stage_write(0);
    __syncthreads();

    f32x4 outv[2] = {{0.f,0.f,0.f,0.f},{0.f,0.f,0.f,0.f}};   // [rf][r]

    for (int ti = 0; ti < NT; ++ti) {
        const int t = t0 + ti;
        const bool more = (ti + 1 < NT);

        // 1. Issue next tile's global loads (in flight across all of compute).
        if (more) stage_load(t + 1);

        // 2. This tile's b1/W2 lane-slices (tiny, L2-hot; consumed after MFMAs).
        float b1v[4], w2v[4];
        #pragma unroll
        for (int nf = 0; nf < 4; ++nf) {
            b1v[nf] = b1[t * 64 + nf * 16 + l15];
            w2v[nf] = W2[t * 64 + nf * 16 + l15];
        }

        // 3. Compute tile ti from bf16 LDS (swizzled reads, 8 x ds_read_b128).
        const char* lb = (const char*)&tile[ti & 1][0];
        f32x4 acc[2][4];
        #pragma unroll
        for (int rf = 0; rf < 2; ++rf)
            #pragma unroll
            for (int nf = 0; nf < 4; ++nf)
                acc[rf][nf] = (f32x4){0.f, 0.f, 0.f, 0.f};

        #pragma unroll
        for (int nf = 0; nf < 4; ++nf) {
            const int j  = nf * 16 + l15;
            const int m  = (j & 7) << 4;
            const int rb = j * 128 + l4 * 16;   // semantic byte of k-slice ks=0
            const bf16x8 bks0 = *reinterpret_cast<const bf16x8*>(lb + (rb ^ m));
            const bf16x8 bks1 = *reinterpret_cast<const bf16x8*>(lb + ((rb + 64) ^ m));
            #pragma unroll
            for (int rf = 0; rf < 2; ++rf) {
                acc[rf][nf] = __builtin_amdgcn_mfma_f32_16x16x32_bf16(
                    afrag[rf][0], bks0, acc[rf][nf], 0, 0, 0);
                acc[rf][nf] = __builtin_amdgcn_mfma_f32_16x16x32_bf16(
                    afrag[rf][1], bks1, acc[rf][nf], 0, 0, 0);
            }
        }

        // 4. Stage 2: y[b,t] = 2*(sum_j relu(h+b1)*W2 + b2); 16-lane butterfly
        //    leaves the sum in all lanes; lane l15==ti keeps tile ti.
        #pragma unroll
        for (int rf = 0; rf < 2; ++rf) {
            #pragma unroll
            for (int r = 0; r < 4; ++r) {
                float s = 0.f;
                #pragma unroll
                for (int nf = 0; nf < 4; ++nf) {
                    const float p = fmaxf(acc[rf][nf][r] + b1v[nf], 0.f);
                    s = fmaf(p, w2v[nf], s);
                }
                s += __shfl_xor(s, 1);
                s += __shfl_xor(s, 2);
                s += __shfl_xor(s, 4);
                s += __shfl_xor(s, 8);
                const float v = 2.f * (s + b2lane);
                outv[rf][r] = (l15 == ti) ? v : outv[rf][r];
            }
        }

        // 5. Convert+write next tile into the other buffer, then one barrier.
        //    WAR vs compute(ti-1) guarded by the barrier at end of iter ti-1.
        if (more) stage_write((ti + 1) & 1);
        __syncthreads();
    }

    // Epilogue: lanes l15=0..7 hold tiles t0..t0+7 -> 32B contiguous stores.
    if (l15 < NT) {
        #pragma unroll
        for (int rf = 0; rf < 2; ++rf)
            #pragma unroll
            for (int r = 0; r < 4; ++r) {
                const int brow = wave * 32 + rf * 16 + l4 * 4 + r;
                out[(size_t)brow * T_DIM + t0 + l15] = outv[rf][r];
            }
    }
}

extern "C" void kernel_launch(void* const* d_in, const int* in_sizes, int n_in,
                              void* d_out, int out_size, void* d_ws, size_t ws_size,
                              hipStream_t stream) {
    const float* x  = (const float*)d_in[0];
    const float* W1 = (const float*)d_in[1];
    const float* b1 = (const float*)d_in[2];
    const float* W2 = (const float*)d_in[3];
    const float* b2 = (const float*)d_in[4];
    float* out = (float*)d_out;

    dim3 grid(T_DIM / NT);   // 2048 blocks
    dim3 block(256);
    hipLaunchKernelGGL(fgbn_kernel, grid, block, 0, stream,
                       x, W1, b1, W2, b2, out);
}

// Round 7
// 59.186 us; speedup vs baseline: 2.1321x; 2.1321x over previous
//
#include <hip/hip_runtime.h>
#include <hip/hip_bf16.h>

namespace {

constexpr int T_DIM = 16384;   // number of tiles
constexpr int NT    = 8;       // tiles per block -> grid = 2048 (no 4-block grid cap)

typedef __attribute__((ext_vector_type(8))) short bf16x8;
typedef __attribute__((ext_vector_type(4))) float f32x4;

__device__ inline short f2bf(float f) {
    union { __hip_bfloat16 h; short s; } u;
    u.h = __float2bfloat16(f);
    return u.s;
}

__device__ inline bf16x8 cvt8(f32x4 a, f32x4 b) {
    bf16x8 r;
    r[0] = f2bf(a[0]); r[1] = f2bf(a[1]); r[2] = f2bf(a[2]); r[3] = f2bf(a[3]);
    r[4] = f2bf(b[0]); r[5] = f2bf(b[1]); r[6] = f2bf(b[2]); r[7] = f2bf(b[3]);
    return r;
}

} // namespace

// EXACT R2 schedule (best measured: 58.3us) with one lever -- occupancy:
//  - NT=8 -> grid 2048 (R2's grid of 1024 hard-capped residency at 4 blocks/CU)
//  - b1/W2 via register prefetch (R1-proven) instead of LDS staging
//    -> LDS = 2 x 16KB = 32KB -> 5 blocks/CU LDS-limit.
//  - launch_bounds(256,4): cap 128 VGPR, zero spill risk (R6 lesson: never
//    force the allocator below its need).
// Per iter: issue DMA(ti+1) -> compute(ti) -> __syncthreads (drain+WAR).
__global__ __launch_bounds__(256, 4) void fgbn_kernel(
    const float* __restrict__ x,
    const float* __restrict__ W1,
    const float* __restrict__ b1,
    const float* __restrict__ W2,
    const float* __restrict__ b2,
    float* __restrict__ out)
{
    __shared__ float tile[2][4096];   // 2 x 16 KB f32 W1 tiles

    const int tid  = threadIdx.x;
    const int lane = tid & 63;
    const int wave = tid >> 6;
    const int l15  = lane & 15;
    const int l4   = lane >> 4;
    const int t0   = blockIdx.x * NT;

    // A fragments from x: A[row=lane&15][k=8*(lane>>4)+e]; wave w owns rows
    // [32w, 32w+32) as two 16-row fragments.
    bf16x8 afrag[2][2];   // [rf][ks]
    #pragma unroll
    for (int rf = 0; rf < 2; ++rf) {
        const int row = wave * 32 + rf * 16 + l15;
        #pragma unroll
        for (int ks = 0; ks < 2; ++ks) {
            const float* src = x + row * 64 + ks * 32 + l4 * 8;
            afrag[rf][ks] = cvt8(*reinterpret_cast<const f32x4*>(src),
                                 *reinterpret_cast<const f32x4*>(src + 4));
        }
    }
    // Lane keeps b2[t0 + l15]; the surviving lane l15==ti consumes it (ti<8).
    const float b2lane = b2[t0 + l15];

    // One 16 KB W1 tile -> tile[buf]; 4 x 16B DMA per thread.
    // Swizzle (both-sides rule): LDS dest linear, global SOURCE chunk
    // pre-swizzled g = c ^ ((c>>4)&7); fragment reads apply the same XOR.
    auto stage = [&](int buf, int t) {
        const char* w1t = (const char*)W1 + (size_t)t * 16384;
        #pragma unroll
        for (int it = 0; it < 4; ++it) {
            const int c = wave * 256 + it * 64 + lane;   // linear LDS chunk
            const int g = c ^ ((c >> 4) & 7);            // pre-swizzled global chunk
            __builtin_amdgcn_global_load_lds(
                (const __attribute__((address_space(1))) unsigned int*)(w1t + (size_t)g * 16),
                (__attribute__((address_space(3))) unsigned int*)&tile[buf][c * 4],
                16, 0, 0);
        }
    };

    // Prologue: tile-0 per-tile vectors (direct, L2-hot) + tile-0 stage.
    float b1v[4], w2v[4];
    #pragma unroll
    for (int nf = 0; nf < 4; ++nf) {
        b1v[nf] = b1[t0 * 64 + nf * 16 + l15];
        w2v[nf] = W2[t0 * 64 + nf * 16 + l15];
    }
    stage(0, t0);
    __syncthreads();

    f32x4 outv[2] = {{0.f,0.f,0.f,0.f},{0.f,0.f,0.f,0.f}};   // [rf][r]

    for (int ti = 0; ti < NT; ++ti) {
        const int t = t0 + ti;
        const bool more = (ti + 1 < NT);

        // 1. Issue DMA for tile ti+1 + register-prefetch its b1/W2 slices.
        float b1n[4], w2n[4];
        if (more) {
            stage((ti + 1) & 1, t + 1);
            #pragma unroll
            for (int nf = 0; nf < 4; ++nf) {
                b1n[nf] = b1[(t + 1) * 64 + nf * 16 + l15];
                w2n[nf] = W2[(t + 1) * 64 + nf * 16 + l15];
            }
        }

        // 2. Compute tile ti from tile[ti&1] (swizzled reads, f32 -> bf16).
        const float* lbuf = tile[ti & 1];
        f32x4 acc[2][4];
        #pragma unroll
        for (int rf = 0; rf < 2; ++rf)
            #pragma unroll
            for (int nf = 0; nf < 4; ++nf)
                acc[rf][nf] = (f32x4){0.f, 0.f, 0.f, 0.f};

        #pragma unroll
        for (int nf = 0; nf < 4; ++nf) {
            const int j = nf * 16 + l15;
            const int sw = j & 7;
            bf16x8 bks[2];
            #pragma unroll
            for (int ks = 0; ks < 2; ++ks) {
                const int c0 = j * 16 + ks * 8 + l4 * 2;
                bks[ks] = cvt8(*reinterpret_cast<const f32x4*>(&lbuf[(c0 ^ sw) * 4]),
                               *reinterpret_cast<const f32x4*>(&lbuf[((c0 + 1) ^ sw) * 4]));
            }
            #pragma unroll
            for (int ks = 0; ks < 2; ++ks)
                #pragma unroll
                for (int rf = 0; rf < 2; ++rf)
                    acc[rf][nf] = __builtin_amdgcn_mfma_f32_16x16x32_bf16(
                        afrag[rf][ks], bks[ks], acc[rf][nf], 0, 0, 0);
        }

        // 3. Stage 2: y[b,t] = 2*(sum_j relu(h+b1)*W2 + b2); 16-lane butterfly
        //    leaves the sum in all lanes; lane l15==ti keeps tile ti.
        #pragma unroll
        for (int rf = 0; rf < 2; ++rf) {
            #pragma unroll
            for (int r = 0; r < 4; ++r) {
                float s = 0.f;
                #pragma unroll
                for (int nf = 0; nf < 4; ++nf) {
                    const float p = fmaxf(acc[rf][nf][r] + b1v[nf], 0.f);
                    s = fmaf(p, w2v[nf], s);
                }
                s += __shfl_xor(s, 1);
                s += __shfl_xor(s, 2);
                s += __shfl_xor(s, 4);
                s += __shfl_xor(s, 8);
                const float v = 2.f * (s + b2lane);
                outv[rf][r] = (l15 == ti) ? v : outv[rf][r];
            }
        }

        if (more) {
            #pragma unroll
            for (int nf = 0; nf < 4; ++nf) { b1v[nf] = b1n[nf]; w2v[nf] = w2n[nf]; }
        }

        // 4. One barrier: drains DMA(ti+1) (RAW for next iter) and guards the
        //    WAR on tile[ti&1] (overwritten by stage(ti+2) next iter).
        __syncthreads();
    }

    // Epilogue: lanes l15=0..7 hold tiles t0..t0+7 -> 32B contiguous stores.
    if (l15 < NT) {
        #pragma unroll
        for (int rf = 0; rf < 2; ++rf)
            #pragma unroll
            for (int r = 0; r < 4; ++r) {
                const int brow = wave * 32 + rf * 16 + l4 * 4 + r;
                out[(size_t)brow * T_DIM + t0 + l15] = outv[rf][r];
            }
    }
}

extern "C" void kernel_launch(void* const* d_in, const int* in_sizes, int n_in,
                              void* d_out, int out_size, void* d_ws, size_t ws_size,
                              hipStream_t stream) {
    const float* x  = (const float*)d_in[0];
    const float* W1 = (const float*)d_in[1];
    const float* b1 = (const float*)d_in[2];
    const float* W2 = (const float*)d_in[3];
    const float* b2 = (const float*)d_in[4];
    float* out = (float*)d_out;

    dim3 grid(T_DIM / NT);   // 2048 blocks
    dim3 block(256);
    hipLaunchKernelGGL(fgbn_kernel, grid, block, 0, stream,
                       x, W1, b1, W2, b2, out);
}